// Round 9
// baseline (628.736 us; speedup 1.0000x reference)
//
#include <hip/hip_runtime.h>
#include <hip/hip_bf16.h>

// ---------------------------------------------------------------------------
// EdgePredModel: NodeMLP + 2x GATv2 + EdgeMLP.
// R9: fp16 fs-gather in GAT (halves dominant gather traffic; src fc output
//     written only as fp16), 128-row blocks for g2-fc and S/D-fc (halves
//     B-fragment L2 re-reads). Edge kernel unchanged from R8.
// ---------------------------------------------------------------------------
constexpr int N_NODES = 20000;
constexpr int N_EDGES = 320000;

typedef _Float16 half8 __attribute__((ext_vector_type(8)));
typedef _Float16 half4 __attribute__((ext_vector_type(4)));
typedef float    f32x16 __attribute__((ext_vector_type(16)));

__device__ __forceinline__ float lrelu(float x) { return x > 0.f ? x : 0.2f * x; }

// ------------------------------ CSR build ---------------------------------
__global__ void hist_kernel(const int* __restrict__ dst, int* __restrict__ counts) {
    int e = blockIdx.x * 256 + threadIdx.x;
    if (e < N_EDGES) atomicAdd(&counts[dst[e]], 1);
}

// single-block exclusive scan of 20000 counts -> row_off, cursor
__global__ void scan_all_kernel(const int* __restrict__ counts,
                                int* __restrict__ row_off, int* __restrict__ cursor) {
    __shared__ int ps[1024];
    const int t = threadIdx.x;
    const int base = t * 20;
    int loc[20];
    int sum = 0;
#pragma unroll
    for (int i = 0; i < 20; ++i) {
        const int idx = base + i;
        const int v = (idx < N_NODES) ? counts[idx] : 0;
        loc[i] = sum;
        sum += v;
    }
    ps[t] = sum;
    __syncthreads();
    for (int off = 1; off < 1024; off <<= 1) {
        const int v = (t >= off) ? ps[t - off] : 0;
        __syncthreads();
        ps[t] += v;
        __syncthreads();
    }
    const int ex = ps[t] - sum;     // exclusive prefix of this thread's chunk
#pragma unroll
    for (int i = 0; i < 20; ++i) {
        const int idx = base + i;
        if (idx < N_NODES) {
            row_off[idx] = ex + loc[i];
            cursor[idx]  = ex + loc[i];
        }
    }
    if (t == 0) row_off[N_NODES] = N_EDGES;
}

__global__ void scatter_kernel(const int* __restrict__ src, const int* __restrict__ dst,
                               int* __restrict__ cursor, int* __restrict__ eidx,
                               int* __restrict__ srcs) {
    int e = blockIdx.x * 256 + threadIdx.x;
    if (e < N_EDGES) {
        int p = atomicAdd(&cursor[dst[e]], 1);
        eidx[p] = e;
        srcs[p] = src[e];
    }
}

// --------------------- merged W prepack into B-fragments -------------------
template <int K, int M>
__device__ __forceinline__ void pack_one(int idx, const float* __restrict__ W,
                                         int r1, int k1, int r2, int joff, int ldw,
                                         _Float16* __restrict__ H,
                                         _Float16* __restrict__ L) {
    const int l  = idx & 63;
    const int t  = (idx >> 6) % (M / 32);
    const int s  = (idx >> 6) / (M / 32);
    const int j  = joff + t * 32 + (l & 31);
    const int kb = s * 16 + (l >> 5) * 8;
    half8 vh, vl;
#pragma unroll
    for (int i = 0; i < 8; ++i) {
        const int k    = kb + i;
        const int rrow = (k < k1) ? (r1 + k) : (r2 + (k - k1));
        const float w  = W[(size_t)rrow * ldw + j];
        const _Float16 h = (_Float16)w;
        vh[i] = h;
        vl[i] = (_Float16)(w - (float)h);
    }
    reinterpret_cast<half8*>(H)[idx] = vh;
    reinterpret_cast<half8*>(L)[idx] = vl;
}

// segment offsets in half8 units
constexpr int OFF_W1  = 0;        // ew1  512x256 -> 16384
constexpr int OFF_G1S = 16384;    // g1ws  64x256 ->  2048
constexpr int OFF_G1D = 18432;
constexpr int OFF_G2S = 20480;    // g2ws 256x256 ->  8192
constexpr int OFF_G2D = 28672;
constexpr int OFF_SW0 = 36864;    // ew0-S cols 0-255   -> 12288
constexpr int OFF_SW1 = 49152;    // ew0-S cols 256-511
constexpr int OFF_DW0 = 61440;    // ew0-D cols 0-255
constexpr int OFF_DW1 = 73728;
constexpr int OFF_N0  = 86016;    // nw0 64x128 -> 1024
constexpr int OFF_N1  = 87040;    // nw1 128x128 -> 2048
constexpr int PACK_TOT = 89088;   // total half8

struct PackIn {
    const float *ew1, *g1ws, *g1wd, *g2ws, *g2wd, *ew0, *nw0, *nw1;
    _Float16 *H, *L;
};

__global__ void prepack_all_kernel(PackIn a) {
    const int idx = blockIdx.x * 256 + threadIdx.x;
    if (idx >= PACK_TOT) return;
    _Float16* H = a.H;
    _Float16* L = a.L;
    if (idx < OFF_G1S)
        pack_one<512, 256>(idx - OFF_W1, a.ew1, 0, 512, 0, 0, 256,
                           H + OFF_W1 * 8, L + OFF_W1 * 8);
    else if (idx < OFF_G1D)
        pack_one<64, 256>(idx - OFF_G1S, a.g1ws, 0, 64, 0, 0, 256,
                          H + OFF_G1S * 8, L + OFF_G1S * 8);
    else if (idx < OFF_G2S)
        pack_one<64, 256>(idx - OFF_G1D, a.g1wd, 0, 64, 0, 0, 256,
                          H + OFF_G1D * 8, L + OFF_G1D * 8);
    else if (idx < OFF_G2D)
        pack_one<256, 256>(idx - OFF_G2S, a.g2ws, 0, 256, 0, 0, 256,
                           H + OFF_G2S * 8, L + OFF_G2S * 8);
    else if (idx < OFF_SW0)
        pack_one<256, 256>(idx - OFF_G2D, a.g2wd, 0, 256, 0, 0, 256,
                           H + OFF_G2D * 8, L + OFF_G2D * 8);
    else if (idx < OFF_SW1)
        pack_one<384, 256>(idx - OFF_SW0, a.ew0, 0, 128, 256, 0, 512,
                           H + OFF_SW0 * 8, L + OFF_SW0 * 8);
    else if (idx < OFF_DW0)
        pack_one<384, 256>(idx - OFF_SW1, a.ew0, 0, 128, 256, 256, 512,
                           H + OFF_SW1 * 8, L + OFF_SW1 * 8);
    else if (idx < OFF_DW1)
        pack_one<384, 256>(idx - OFF_DW0, a.ew0, 128, 128, 512, 0, 512,
                           H + OFF_DW0 * 8, L + OFF_DW0 * 8);
    else if (idx < OFF_N0)
        pack_one<384, 256>(idx - OFF_DW1, a.ew0, 128, 128, 512, 256, 512,
                           H + OFF_DW1 * 8, L + OFF_DW1 * 8);
    else if (idx < OFF_N1)
        pack_one<64, 128>(idx - OFF_N0, a.nw0, 0, 64, 0, 0, 128,
                          H + OFF_N0 * 8, L + OFF_N0 * 8);
    else
        pack_one<128, 128>(idx - OFF_N1, a.nw1, 0, 128, 0, 0, 128,
                           H + OFF_N1 * 8, L + OFF_N1 * 8);
}

// ----------------------- split-fp16 MFMA node linear -----------------------
// Per-jb outputs: fp32 y (optional) and/or fp16 yh (optional).
struct LinOut { float* y[4]; const float* b[4]; _Float16* yh[4]; };

// WR: waves acting as row groups (1, 2, or 4). Block rows = 32*WR.
template <int K, int TJ, int WR, int K1, int LD1, int LD2, int LDY,
          bool RELU, int MINW, int SEG>
__global__ __launch_bounds__(256, MINW) void mfma_linear2_kernel(
    const float* __restrict__ X1, const float* __restrict__ X2,
    const _Float16* __restrict__ BHp, const _Float16* __restrict__ BLp,
    LinOut lo, int N) {
    constexpr int WC    = 4 / WR;
    constexpr int TILES = WC * TJ;
    const int jb  = blockIdx.y;
    const int tid = threadIdx.x;
    const int wv  = tid >> 6, l = tid & 63;
    const int rg  = (WR == 1) ? 0 : ((WR == 4) ? wv : (wv & 1));
    const int cg  = (WR == 1) ? wv : ((WR == 4) ? 0 : (wv >> 1));
    const int m   = l & 31, h = l >> 5;
    const int row = blockIdx.x * (32 * WR) + rg * 32 + m;
    const int ar  = (row < N) ? row : (N - 1);
    const float* __restrict__ xr1 = X1 + (size_t)ar * LD1;
    const float* __restrict__ xr2 = X2 + (size_t)ar * LD2;
    const half8* __restrict__ BH = reinterpret_cast<const half8*>(BHp) + (size_t)jb * SEG;
    const half8* __restrict__ BL = reinterpret_cast<const half8*>(BLp) + (size_t)jb * SEG;
    const float* __restrict__ bp = lo.b[jb];
    float* __restrict__ Y = lo.y[jb];
    _Float16* __restrict__ Yh = lo.yh[jb];

    f32x16 acc[TJ];
#pragma unroll
    for (int jt = 0; jt < TJ; ++jt) {
        const float bv = bp ? bp[cg * TJ * 32 + jt * 32 + m] : 0.f;
#pragma unroll
        for (int r = 0; r < 16; ++r) acc[jt][r] = bv;
    }

    const int kf = h * 8;
    const float* pf = (kf < K1) ? (xr1 + kf) : (xr2 + (kf - K1));
    float4 xa = *reinterpret_cast<const float4*>(pf);
    float4 xb = *reinterpret_cast<const float4*>(pf + 4);

    for (int s = 0; s < K / 16; ++s) {
        const float xs[8] = {xa.x, xa.y, xa.z, xa.w, xb.x, xb.y, xb.z, xb.w};
        if (s + 1 < K / 16) {
            const int kn = (s + 1) * 16 + h * 8;
            const float* pn = (kn < K1) ? (xr1 + kn) : (xr2 + (kn - K1));
            xa = *reinterpret_cast<const float4*>(pn);
            xb = *reinterpret_cast<const float4*>(pn + 4);
        }
        half8 ah, al;
#pragma unroll
        for (int i = 0; i < 8; ++i) {
            const _Float16 hi = (_Float16)xs[i];
            ah[i] = hi;
            al[i] = (_Float16)(xs[i] - (float)hi);
        }
#pragma unroll
        for (int jt = 0; jt < TJ; ++jt) {
            const int fi = (s * TILES + cg * TJ + jt) * 64 + l;
            const half8 bh = BH[fi];
            const half8 bl = BL[fi];
            acc[jt] = __builtin_amdgcn_mfma_f32_32x32x16_f16(ah, bh, acc[jt], 0, 0, 0);
            acc[jt] = __builtin_amdgcn_mfma_f32_32x32x16_f16(al, bh, acc[jt], 0, 0, 0);
            acc[jt] = __builtin_amdgcn_mfma_f32_32x32x16_f16(ah, bl, acc[jt], 0, 0, 0);
        }
    }

    const int rbase = blockIdx.x * (32 * WR) + rg * 32;
#pragma unroll
    for (int jt = 0; jt < TJ; ++jt) {
        const int j = cg * TJ * 32 + jt * 32 + m;
#pragma unroll
        for (int r = 0; r < 16; ++r) {
            const int orow = rbase + (r & 3) + 8 * (r >> 2) + 4 * h;
            if (orow < N) {
                float v = acc[jt][r];
                if (RELU) v = fmaxf(v, 0.f);
                if (Y)  Y[(size_t)orow * LDY + j] = v;
                if (Yh) Yh[(size_t)orow * LDY + j] = (_Float16)v;
            }
        }
    }
}

// --------------------------- fused GATv2 layer -----------------------------
// fs gathered as fp16 (halved traffic); fd fp32 (one row per node).
__global__ void gat_fused_kernel(const _Float16* __restrict__ fsh,
                                 const float* __restrict__ fd,
                                 const float* __restrict__ attn,
                                 const int* __restrict__ row_off,
                                 const int* __restrict__ srcs,
                                 float* __restrict__ outp) {
    const int wv = threadIdx.x >> 6, l = threadIdx.x & 63;
    const int n = blockIdx.x * 4 + wv;
    if (n >= N_NODES) return;
    const int base = (l >> 5) * 128 + (l & 31) * 4;    // h*128 + d
    const float4 fdv = *reinterpret_cast<const float4*>(&fd[n * 256 + base]);
    const float4 av  = *reinterpret_cast<const float4*>(&attn[base]);
    const int s0 = row_off[n], s1 = row_off[n + 1];

    float m = -INFINITY, lsum = 0.f;
    float4 acc = {0.f, 0.f, 0.f, 0.f};
    half4 v0 = {0, 0, 0, 0}, v1 = {0, 0, 0, 0};
    if (s0 < s1)
        v0 = *reinterpret_cast<const half4*>(&fsh[(size_t)srcs[s0] * 256 + base]);
    if (s0 + 1 < s1)
        v1 = *reinterpret_cast<const half4*>(&fsh[(size_t)srcs[s0 + 1] * 256 + base]);
    for (int i = s0; i < s1; ++i) {
        const float4 vc = {(float)v0.x, (float)v0.y, (float)v0.z, (float)v0.w};
        v0 = v1;
        if (i + 2 < s1)                                  // depth-2 pipeline
            v1 = *reinterpret_cast<const half4*>(&fsh[(size_t)srcs[i + 2] * 256 + base]);
        float p = lrelu(vc.x + fdv.x) * av.x;
        p = fmaf(lrelu(vc.y + fdv.y), av.y, p);
        p = fmaf(lrelu(vc.z + fdv.z), av.z, p);
        p = fmaf(lrelu(vc.w + fdv.w), av.w, p);
#pragma unroll
        for (int off = 1; off < 32; off <<= 1) p += __shfl_xor(p, off);
        const float mn = fmaxf(m, p);
        const float alpha = __expf(m - mn);              // first iter: exp(-inf)=0
        const float w = __expf(p - mn);
        lsum = fmaf(lsum, alpha, w);
        acc.x = fmaf(acc.x, alpha, w * vc.x);
        acc.y = fmaf(acc.y, alpha, w * vc.y);
        acc.z = fmaf(acc.z, alpha, w * vc.z);
        acc.w = fmaf(acc.w, alpha, w * vc.w);
        m = mn;
    }
    const float inv = (s1 > s0) ? 1.f / lsum : 0.f;
    float4 o;
    o.x = fmaxf(acc.x * inv, 0.f);
    o.y = fmaxf(acc.y * inv, 0.f);
    o.z = fmaxf(acc.z * inv, 0.f);
    o.w = fmaxf(acc.w * inv, 0.f);
    *reinterpret_cast<float4*>(&outp[n * 256 + base]) = o;
}

// ------------------------------ fused EdgeMLP v6 ---------------------------
// (unchanged from R8) 2-product split; B hi double-buffered in 16 KB LDS.
__global__ __launch_bounds__(256, 2) void edge_mlp6_kernel(
    const float* __restrict__ S, const float* __restrict__ Dn,
    const int* __restrict__ srcs, const int* __restrict__ eidx,
    const int* __restrict__ dstf,
    const _Float16* __restrict__ WpH,
    const float* __restrict__ b1, const float* __restrict__ w2,
    const float* __restrict__ b2, float* __restrict__ out) {
    __shared__ __align__(16) _Float16 Bs[2][8][512];   // 16 KB
    const int tid = threadIdx.x;
    const int wv  = tid >> 6, l = tid & 63;
    const int m   = l & 31, h = l >> 5;
    const int e0  = blockIdx.x * 128;
    const int slot = e0 + wv * 32 + m;
    const float* __restrict__ Srow = S  + (size_t)srcs[slot] * 512;
    const float* __restrict__ Drow = Dn + (size_t)dstf[eidx[slot]] * 512;

    f32x16 acc[8];
#pragma unroll
    for (int jt = 0; jt < 8; ++jt) {
        const float bv = b1[jt * 32 + m];
#pragma unroll
        for (int r = 0; r < 16; ++r) acc[jt][r] = bv;
    }

#pragma unroll
    for (int c = 0; c < 2; ++c) {
        const int jt = wv * 2 + c;
        *reinterpret_cast<float4*>(&Bs[0][jt][l * 8]) =
            *reinterpret_cast<const float4*>(WpH + ((size_t)jt * 64 + l) * 8);
    }
    float4 sa = *reinterpret_cast<const float4*>(Srow + h * 8);
    float4 sb = *reinterpret_cast<const float4*>(Srow + h * 8 + 4);
    float4 da = *reinterpret_cast<const float4*>(Drow + h * 8);
    float4 db = *reinterpret_cast<const float4*>(Drow + h * 8 + 4);
    __syncthreads();

    for (int s = 0; s < 32; ++s) {
        const int buf = s & 1;
        float4 bst[2];
        if (s < 31) {
#pragma unroll
            for (int c = 0; c < 2; ++c) {
                const int jt = wv * 2 + c;
                bst[c] = *reinterpret_cast<const float4*>(
                    WpH + ((size_t)((s + 1) * 8 + jt) * 64 + l) * 8);
            }
        }
        const float xs[8] = {sa.x + da.x, sa.y + da.y, sa.z + da.z, sa.w + da.w,
                             sb.x + db.x, sb.y + db.y, sb.z + db.z, sb.w + db.w};
        if (s < 31) {
            const int ko = (s + 1) * 16 + h * 8;
            sa = *reinterpret_cast<const float4*>(Srow + ko);
            sb = *reinterpret_cast<const float4*>(Srow + ko + 4);
            da = *reinterpret_cast<const float4*>(Drow + ko);
            db = *reinterpret_cast<const float4*>(Drow + ko + 4);
        }
        half8 ah, al;
#pragma unroll
        for (int i = 0; i < 8; ++i) {
            const float xv = fmaxf(xs[i], 0.f);
            const _Float16 hi = (_Float16)xv;
            ah[i] = hi;
            al[i] = (_Float16)(xv - (float)hi);
        }
#pragma unroll
        for (int jt = 0; jt < 8; ++jt) {
            const half8 bh = *reinterpret_cast<const half8*>(&Bs[buf][jt][l * 8]);
            acc[jt] = __builtin_amdgcn_mfma_f32_32x32x16_f16(ah, bh, acc[jt], 0, 0, 0);
            acc[jt] = __builtin_amdgcn_mfma_f32_32x32x16_f16(al, bh, acc[jt], 0, 0, 0);
        }
        if (s < 31) {
#pragma unroll
            for (int c = 0; c < 2; ++c) {
                const int jt = wv * 2 + c;
                *reinterpret_cast<float4*>(&Bs[buf ^ 1][jt][l * 8]) = bst[c];
            }
        }
        __syncthreads();
    }

    float part[16];
#pragma unroll
    for (int r = 0; r < 16; ++r) part[r] = 0.f;
#pragma unroll
    for (int jt = 0; jt < 8; ++jt) {
        const float w2v = w2[jt * 32 + m];
#pragma unroll
        for (int r = 0; r < 16; ++r)
            part[r] = fmaf(fmaxf(acc[jt][r], 0.f), w2v, part[r]);
    }
#pragma unroll
    for (int off = 1; off < 32; off <<= 1)
#pragma unroll
        for (int r = 0; r < 16; ++r) part[r] += __shfl_xor(part[r], off);
    if (m == 0) {
        const float b2v = b2[0];
#pragma unroll
        for (int r = 0; r < 16; ++r) {
            const int row = (r & 3) + 8 * (r >> 2) + 4 * h;
            out[eidx[e0 + wv * 32 + row]] = part[r] + b2v;
        }
    }
}

// ------------------------------ launch ------------------------------------
extern "C" void kernel_launch(void* const* d_in, const int* in_sizes, int n_in,
                              void* d_out, int out_size, void* d_ws, size_t ws_size,
                              hipStream_t stream) {
    (void)in_sizes; (void)n_in; (void)out_size; (void)ws_size;
    const float* x    = (const float*)d_in[0];
    const int*   src  = (const int*)d_in[1];
    const int*   dst  = (const int*)d_in[2];
    const float* nw0  = (const float*)d_in[3];
    const float* nb0  = (const float*)d_in[4];
    const float* nw1  = (const float*)d_in[5];
    const float* nb1  = (const float*)d_in[6];
    const float* g1ws = (const float*)d_in[7];
    const float* g1bs = (const float*)d_in[8];
    const float* g1wd = (const float*)d_in[9];
    const float* g1bd = (const float*)d_in[10];
    const float* g1a  = (const float*)d_in[11];
    const float* g2ws = (const float*)d_in[12];
    const float* g2bs = (const float*)d_in[13];
    const float* g2wd = (const float*)d_in[14];
    const float* g2bd = (const float*)d_in[15];
    const float* g2a  = (const float*)d_in[16];
    const float* ew0  = (const float*)d_in[17];
    const float* eb0  = (const float*)d_in[18];
    const float* ew1  = (const float*)d_in[19];
    const float* eb1  = (const float*)d_in[20];
    const float* ew2  = (const float*)d_in[21];
    const float* eb2  = (const float*)d_in[22];
    float* out = (float*)d_out;

    float* wsF = (float*)d_ws;
    float* h1  = wsF;                       // 20000*128
    float* g2o = wsF + 2560000;             // 20000*256
    float* fsb = wsF + 7680000;             // 20000*256 (NodeMLP scratch)
    float* fdb = wsF + 12800000;            // 20000*256
    float* g1o = wsF + 17920000;            // 20000*256
    float* Sb  = wsF + 7680000;             // 20000*512 overlays fsb+fdb (dead)
    float* Db  = wsF + 17920000;            // 20000*512 overlays g1o+fsh (dead)
    _Float16* fsh = (_Float16*)(wsF + 23040000);   // 20000*256 fp16, dead before Db
    int* wsI     = (int*)(wsF + 28160000);
    int* row_off = wsI;                     // [0, 20016)
    int* cursor  = wsI + 20016;             // [20016, 40032)
    int* eidx    = wsI + 40032;             // [40032, 360032)
    int* srcs    = wsI + 360032;            // [360032, 680032)
    // ---- B-fragment pack region (tail) ----
    _Float16* pkH = (_Float16*)((char*)d_ws + 115361280);
    _Float16* pkL = pkH + (size_t)PACK_TOT * 8;

    // ---- CSR build ----
    hipMemsetAsync(cursor, 0, N_NODES * sizeof(int), stream);
    hist_kernel<<<1250, 256, 0, stream>>>(dst, cursor);
    scan_all_kernel<<<1, 1024, 0, stream>>>(cursor, row_off, cursor);
    scatter_kernel<<<1250, 256, 0, stream>>>(src, dst, cursor, eidx, srcs);

    // ---- merged weight prepack ----
    PackIn pin{ew1, g1ws, g1wd, g2ws, g2wd, ew0, nw0, nw1, pkH, pkL};
    prepack_all_kernel<<<(PACK_TOT + 255) / 256, 256, 0, stream>>>(pin);

    // ---- NodeMLP ----
    {   LinOut lo{{fsb, nullptr, nullptr, nullptr}, {nb0, nullptr, nullptr, nullptr},
                  {nullptr, nullptr, nullptr, nullptr}};
        mfma_linear2_kernel<64, 1, 1, 64, 64, 64, 128, true, 4, 0>
            <<<dim3(625, 1), 256, 0, stream>>>(x, x, pkH + OFF_N0 * 8, pkL + OFF_N0 * 8,
                                               lo, N_NODES); }
    {   LinOut lo{{h1, nullptr, nullptr, nullptr}, {nb1, nullptr, nullptr, nullptr},
                  {nullptr, nullptr, nullptr, nullptr}};
        mfma_linear2_kernel<128, 1, 1, 128, 128, 128, 128, true, 4, 0>
            <<<dim3(625, 1), 256, 0, stream>>>(fsb, fsb, pkH + OFF_N1 * 8, pkL + OFF_N1 * 8,
                                               lo, N_NODES); }

    // ---- GATv2 layer 1: fused fc (src fp16 | dst fp32), fused attention ----
    {   LinOut lo{{nullptr, fdb, nullptr, nullptr}, {g1bs, g1bd, nullptr, nullptr},
                  {fsh, nullptr, nullptr, nullptr}};
        mfma_linear2_kernel<64, 2, 1, 64, 64, 64, 256, false, 4, 2048>
            <<<dim3(625, 2), 256, 0, stream>>>(x, x, pkH + OFF_G1S * 8, pkL + OFF_G1S * 8,
                                               lo, N_NODES); }
    gat_fused_kernel<<<5000, 256, 0, stream>>>(fsh, fdb, g1a, row_off, srcs, g1o);

    // ---- GATv2 layer 2 (128-row blocks: WR=4, TJ=8) ----
    {   LinOut lo{{nullptr, fdb, nullptr, nullptr}, {g2bs, g2bd, nullptr, nullptr},
                  {fsh, nullptr, nullptr, nullptr}};
        mfma_linear2_kernel<256, 8, 4, 256, 256, 256, 256, false, 2, 8192>
            <<<dim3(157, 2), 256, 0, stream>>>(g1o, g1o, pkH + OFF_G2S * 8, pkL + OFF_G2S * 8,
                                               lo, N_NODES); }
    gat_fused_kernel<<<5000, 256, 0, stream>>>(fsh, fdb, g2a, row_off, srcs, g2o);

    // ---- fused S|D precompute (128-row blocks: WR=4, TJ=8) ----
    {   LinOut lo{{Sb, Sb + 256, Db, Db + 256}, {nullptr, nullptr, eb0, eb0 + 256},
                  {nullptr, nullptr, nullptr, nullptr}};
        mfma_linear2_kernel<384, 8, 4, 128, 128, 256, 512, false, 2, 12288>
            <<<dim3(157, 4), 256, 0, stream>>>(h1, g2o, pkH + OFF_SW0 * 8, pkL + OFF_SW0 * 8,
                                               lo, N_NODES); }

    // ---- fused EdgeMLP v6 (2-product) ----
    edge_mlp6_kernel<<<N_EDGES / 128, 256, 0, stream>>>(Sb, Db, srcs, eidx, dst,
                                                        pkH + OFF_W1 * 8,
                                                        eb1, ew2, eb2, out);
}

// Round 10
// 542.354 us; speedup vs baseline: 1.1593x; 1.1593x over previous
//
#include <hip/hip_runtime.h>
#include <hip/hip_bf16.h>

// ---------------------------------------------------------------------------
// EdgePredModel: NodeMLP + 2x GATv2 + EdgeMLP.
// R10: fp16 S/D (halved edge gather bytes) + single-product MFMA in the edge
//      kernel (8 MFMA/wave-step). S/D fc emits fp16 directly. Node side
//      unchanged from R9.
// ---------------------------------------------------------------------------
constexpr int N_NODES = 20000;
constexpr int N_EDGES = 320000;

typedef _Float16 half8 __attribute__((ext_vector_type(8)));
typedef _Float16 half4 __attribute__((ext_vector_type(4)));
typedef float    f32x16 __attribute__((ext_vector_type(16)));

__device__ __forceinline__ float lrelu(float x) { return x > 0.f ? x : 0.2f * x; }

// ------------------------------ CSR build ---------------------------------
__global__ void hist_kernel(const int* __restrict__ dst, int* __restrict__ counts) {
    int e = blockIdx.x * 256 + threadIdx.x;
    if (e < N_EDGES) atomicAdd(&counts[dst[e]], 1);
}

// single-block exclusive scan of 20000 counts -> row_off, cursor
__global__ void scan_all_kernel(const int* __restrict__ counts,
                                int* __restrict__ row_off, int* __restrict__ cursor) {
    __shared__ int ps[1024];
    const int t = threadIdx.x;
    const int base = t * 20;
    int loc[20];
    int sum = 0;
#pragma unroll
    for (int i = 0; i < 20; ++i) {
        const int idx = base + i;
        const int v = (idx < N_NODES) ? counts[idx] : 0;
        loc[i] = sum;
        sum += v;
    }
    ps[t] = sum;
    __syncthreads();
    for (int off = 1; off < 1024; off <<= 1) {
        const int v = (t >= off) ? ps[t - off] : 0;
        __syncthreads();
        ps[t] += v;
        __syncthreads();
    }
    const int ex = ps[t] - sum;     // exclusive prefix of this thread's chunk
#pragma unroll
    for (int i = 0; i < 20; ++i) {
        const int idx = base + i;
        if (idx < N_NODES) {
            row_off[idx] = ex + loc[i];
            cursor[idx]  = ex + loc[i];
        }
    }
    if (t == 0) row_off[N_NODES] = N_EDGES;
}

__global__ void scatter_kernel(const int* __restrict__ src, const int* __restrict__ dst,
                               int* __restrict__ cursor, int* __restrict__ eidx,
                               int* __restrict__ srcs) {
    int e = blockIdx.x * 256 + threadIdx.x;
    if (e < N_EDGES) {
        int p = atomicAdd(&cursor[dst[e]], 1);
        eidx[p] = e;
        srcs[p] = src[e];
    }
}

// --------------------- merged W prepack into B-fragments -------------------
template <int K, int M>
__device__ __forceinline__ void pack_one(int idx, const float* __restrict__ W,
                                         int r1, int k1, int r2, int joff, int ldw,
                                         _Float16* __restrict__ H,
                                         _Float16* __restrict__ L) {
    const int l  = idx & 63;
    const int t  = (idx >> 6) % (M / 32);
    const int s  = (idx >> 6) / (M / 32);
    const int j  = joff + t * 32 + (l & 31);
    const int kb = s * 16 + (l >> 5) * 8;
    half8 vh, vl;
#pragma unroll
    for (int i = 0; i < 8; ++i) {
        const int k    = kb + i;
        const int rrow = (k < k1) ? (r1 + k) : (r2 + (k - k1));
        const float w  = W[(size_t)rrow * ldw + j];
        const _Float16 h = (_Float16)w;
        vh[i] = h;
        vl[i] = (_Float16)(w - (float)h);
    }
    reinterpret_cast<half8*>(H)[idx] = vh;
    reinterpret_cast<half8*>(L)[idx] = vl;
}

// segment offsets in half8 units
constexpr int OFF_W1  = 0;        // ew1  512x256 -> 16384
constexpr int OFF_G1S = 16384;    // g1ws  64x256 ->  2048
constexpr int OFF_G1D = 18432;
constexpr int OFF_G2S = 20480;    // g2ws 256x256 ->  8192
constexpr int OFF_G2D = 28672;
constexpr int OFF_SW0 = 36864;    // ew0-S cols 0-255   -> 12288
constexpr int OFF_SW1 = 49152;    // ew0-S cols 256-511
constexpr int OFF_DW0 = 61440;    // ew0-D cols 0-255
constexpr int OFF_DW1 = 73728;
constexpr int OFF_N0  = 86016;    // nw0 64x128 -> 1024
constexpr int OFF_N1  = 87040;    // nw1 128x128 -> 2048
constexpr int PACK_TOT = 89088;   // total half8

struct PackIn {
    const float *ew1, *g1ws, *g1wd, *g2ws, *g2wd, *ew0, *nw0, *nw1;
    _Float16 *H, *L;
};

__global__ void prepack_all_kernel(PackIn a) {
    const int idx = blockIdx.x * 256 + threadIdx.x;
    if (idx >= PACK_TOT) return;
    _Float16* H = a.H;
    _Float16* L = a.L;
    if (idx < OFF_G1S)
        pack_one<512, 256>(idx - OFF_W1, a.ew1, 0, 512, 0, 0, 256,
                           H + OFF_W1 * 8, L + OFF_W1 * 8);
    else if (idx < OFF_G1D)
        pack_one<64, 256>(idx - OFF_G1S, a.g1ws, 0, 64, 0, 0, 256,
                          H + OFF_G1S * 8, L + OFF_G1S * 8);
    else if (idx < OFF_G2S)
        pack_one<64, 256>(idx - OFF_G1D, a.g1wd, 0, 64, 0, 0, 256,
                          H + OFF_G1D * 8, L + OFF_G1D * 8);
    else if (idx < OFF_G2D)
        pack_one<256, 256>(idx - OFF_G2S, a.g2ws, 0, 256, 0, 0, 256,
                           H + OFF_G2S * 8, L + OFF_G2S * 8);
    else if (idx < OFF_SW0)
        pack_one<256, 256>(idx - OFF_G2D, a.g2wd, 0, 256, 0, 0, 256,
                           H + OFF_G2D * 8, L + OFF_G2D * 8);
    else if (idx < OFF_SW1)
        pack_one<384, 256>(idx - OFF_SW0, a.ew0, 0, 128, 256, 0, 512,
                           H + OFF_SW0 * 8, L + OFF_SW0 * 8);
    else if (idx < OFF_DW0)
        pack_one<384, 256>(idx - OFF_SW1, a.ew0, 0, 128, 256, 256, 512,
                           H + OFF_SW1 * 8, L + OFF_SW1 * 8);
    else if (idx < OFF_DW1)
        pack_one<384, 256>(idx - OFF_DW0, a.ew0, 128, 128, 512, 0, 512,
                           H + OFF_DW0 * 8, L + OFF_DW0 * 8);
    else if (idx < OFF_N0)
        pack_one<384, 256>(idx - OFF_DW1, a.ew0, 128, 128, 512, 256, 512,
                           H + OFF_DW1 * 8, L + OFF_DW1 * 8);
    else if (idx < OFF_N1)
        pack_one<64, 128>(idx - OFF_N0, a.nw0, 0, 64, 0, 0, 128,
                          H + OFF_N0 * 8, L + OFF_N0 * 8);
    else
        pack_one<128, 128>(idx - OFF_N1, a.nw1, 0, 128, 0, 0, 128,
                           H + OFF_N1 * 8, L + OFF_N1 * 8);
}

// ----------------------- split-fp16 MFMA node linear -----------------------
// Per-jb outputs: fp32 y (optional) and/or fp16 yh (optional).
struct LinOut { float* y[4]; const float* b[4]; _Float16* yh[4]; };

// WR: waves acting as row groups (1, 2, or 4). Block rows = 32*WR.
template <int K, int TJ, int WR, int K1, int LD1, int LD2, int LDY,
          bool RELU, int MINW, int SEG>
__global__ __launch_bounds__(256, MINW) void mfma_linear2_kernel(
    const float* __restrict__ X1, const float* __restrict__ X2,
    const _Float16* __restrict__ BHp, const _Float16* __restrict__ BLp,
    LinOut lo, int N) {
    constexpr int WC    = 4 / WR;
    constexpr int TILES = WC * TJ;
    const int jb  = blockIdx.y;
    const int tid = threadIdx.x;
    const int wv  = tid >> 6, l = tid & 63;
    const int rg  = (WR == 1) ? 0 : ((WR == 4) ? wv : (wv & 1));
    const int cg  = (WR == 1) ? wv : ((WR == 4) ? 0 : (wv >> 1));
    const int m   = l & 31, h = l >> 5;
    const int row = blockIdx.x * (32 * WR) + rg * 32 + m;
    const int ar  = (row < N) ? row : (N - 1);
    const float* __restrict__ xr1 = X1 + (size_t)ar * LD1;
    const float* __restrict__ xr2 = X2 + (size_t)ar * LD2;
    const half8* __restrict__ BH = reinterpret_cast<const half8*>(BHp) + (size_t)jb * SEG;
    const half8* __restrict__ BL = reinterpret_cast<const half8*>(BLp) + (size_t)jb * SEG;
    const float* __restrict__ bp = lo.b[jb];
    float* __restrict__ Y = lo.y[jb];
    _Float16* __restrict__ Yh = lo.yh[jb];

    f32x16 acc[TJ];
#pragma unroll
    for (int jt = 0; jt < TJ; ++jt) {
        const float bv = bp ? bp[cg * TJ * 32 + jt * 32 + m] : 0.f;
#pragma unroll
        for (int r = 0; r < 16; ++r) acc[jt][r] = bv;
    }

    const int kf = h * 8;
    const float* pf = (kf < K1) ? (xr1 + kf) : (xr2 + (kf - K1));
    float4 xa = *reinterpret_cast<const float4*>(pf);
    float4 xb = *reinterpret_cast<const float4*>(pf + 4);

    for (int s = 0; s < K / 16; ++s) {
        const float xs[8] = {xa.x, xa.y, xa.z, xa.w, xb.x, xb.y, xb.z, xb.w};
        if (s + 1 < K / 16) {
            const int kn = (s + 1) * 16 + h * 8;
            const float* pn = (kn < K1) ? (xr1 + kn) : (xr2 + (kn - K1));
            xa = *reinterpret_cast<const float4*>(pn);
            xb = *reinterpret_cast<const float4*>(pn + 4);
        }
        half8 ah, al;
#pragma unroll
        for (int i = 0; i < 8; ++i) {
            const _Float16 hi = (_Float16)xs[i];
            ah[i] = hi;
            al[i] = (_Float16)(xs[i] - (float)hi);
        }
#pragma unroll
        for (int jt = 0; jt < TJ; ++jt) {
            const int fi = (s * TILES + cg * TJ + jt) * 64 + l;
            const half8 bh = BH[fi];
            const half8 bl = BL[fi];
            acc[jt] = __builtin_amdgcn_mfma_f32_32x32x16_f16(ah, bh, acc[jt], 0, 0, 0);
            acc[jt] = __builtin_amdgcn_mfma_f32_32x32x16_f16(al, bh, acc[jt], 0, 0, 0);
            acc[jt] = __builtin_amdgcn_mfma_f32_32x32x16_f16(ah, bl, acc[jt], 0, 0, 0);
        }
    }

    const int rbase = blockIdx.x * (32 * WR) + rg * 32;
#pragma unroll
    for (int jt = 0; jt < TJ; ++jt) {
        const int j = cg * TJ * 32 + jt * 32 + m;
#pragma unroll
        for (int r = 0; r < 16; ++r) {
            const int orow = rbase + (r & 3) + 8 * (r >> 2) + 4 * h;
            if (orow < N) {
                float v = acc[jt][r];
                if (RELU) v = fmaxf(v, 0.f);
                if (Y)  Y[(size_t)orow * LDY + j] = v;
                if (Yh) Yh[(size_t)orow * LDY + j] = (_Float16)v;
            }
        }
    }
}

// --------------------------- fused GATv2 layer -----------------------------
// fs gathered as fp16; fd fp32 (one row per node).
__global__ void gat_fused_kernel(const _Float16* __restrict__ fsh,
                                 const float* __restrict__ fd,
                                 const float* __restrict__ attn,
                                 const int* __restrict__ row_off,
                                 const int* __restrict__ srcs,
                                 float* __restrict__ outp) {
    const int wv = threadIdx.x >> 6, l = threadIdx.x & 63;
    const int n = blockIdx.x * 4 + wv;
    if (n >= N_NODES) return;
    const int base = (l >> 5) * 128 + (l & 31) * 4;    // h*128 + d
    const float4 fdv = *reinterpret_cast<const float4*>(&fd[n * 256 + base]);
    const float4 av  = *reinterpret_cast<const float4*>(&attn[base]);
    const int s0 = row_off[n], s1 = row_off[n + 1];

    float m = -INFINITY, lsum = 0.f;
    float4 acc = {0.f, 0.f, 0.f, 0.f};
    half4 v0 = {0, 0, 0, 0}, v1 = {0, 0, 0, 0};
    if (s0 < s1)
        v0 = *reinterpret_cast<const half4*>(&fsh[(size_t)srcs[s0] * 256 + base]);
    if (s0 + 1 < s1)
        v1 = *reinterpret_cast<const half4*>(&fsh[(size_t)srcs[s0 + 1] * 256 + base]);
    for (int i = s0; i < s1; ++i) {
        const float4 vc = {(float)v0.x, (float)v0.y, (float)v0.z, (float)v0.w};
        v0 = v1;
        if (i + 2 < s1)                                  // depth-2 pipeline
            v1 = *reinterpret_cast<const half4*>(&fsh[(size_t)srcs[i + 2] * 256 + base]);
        float p = lrelu(vc.x + fdv.x) * av.x;
        p = fmaf(lrelu(vc.y + fdv.y), av.y, p);
        p = fmaf(lrelu(vc.z + fdv.z), av.z, p);
        p = fmaf(lrelu(vc.w + fdv.w), av.w, p);
#pragma unroll
        for (int off = 1; off < 32; off <<= 1) p += __shfl_xor(p, off);
        const float mn = fmaxf(m, p);
        const float alpha = __expf(m - mn);              // first iter: exp(-inf)=0
        const float w = __expf(p - mn);
        lsum = fmaf(lsum, alpha, w);
        acc.x = fmaf(acc.x, alpha, w * vc.x);
        acc.y = fmaf(acc.y, alpha, w * vc.y);
        acc.z = fmaf(acc.z, alpha, w * vc.z);
        acc.w = fmaf(acc.w, alpha, w * vc.w);
        m = mn;
    }
    const float inv = (s1 > s0) ? 1.f / lsum : 0.f;
    float4 o;
    o.x = fmaxf(acc.x * inv, 0.f);
    o.y = fmaxf(acc.y * inv, 0.f);
    o.z = fmaxf(acc.z * inv, 0.f);
    o.w = fmaxf(acc.w * inv, 0.f);
    *reinterpret_cast<float4*>(&outp[n * 256 + base]) = o;
}

// ------------------------------ fused EdgeMLP v7 ---------------------------
// fp16 S/D gather (half bytes) + single-product MFMA (8 per wave-step).
// Block = 128 edges, 4 waves; wave = 32e x 256j. B hi double-buffered in
// 16 KB LDS. Layer-2 folded; scatter store via eidx.
__global__ __launch_bounds__(256, 2) void edge_mlp7_kernel(
    const _Float16* __restrict__ S, const _Float16* __restrict__ Dn,
    const int* __restrict__ srcs, const int* __restrict__ eidx,
    const int* __restrict__ dstf,
    const _Float16* __restrict__ WpH,
    const float* __restrict__ b1, const float* __restrict__ w2,
    const float* __restrict__ b2, float* __restrict__ out) {
    __shared__ __align__(16) _Float16 Bs[2][8][512];   // 16 KB
    const int tid = threadIdx.x;
    const int wv  = tid >> 6, l = tid & 63;
    const int m   = l & 31, h = l >> 5;
    const int e0  = blockIdx.x * 128;
    const int slot = e0 + wv * 32 + m;
    const _Float16* __restrict__ Srow = S  + (size_t)srcs[slot] * 512;
    const _Float16* __restrict__ Drow = Dn + (size_t)dstf[eidx[slot]] * 512;

    f32x16 acc[8];
#pragma unroll
    for (int jt = 0; jt < 8; ++jt) {
        const float bv = b1[jt * 32 + m];
#pragma unroll
        for (int r = 0; r < 16; ++r) acc[jt][r] = bv;
    }

    // stage B(s=0) hi into buf 0: wave wv stages chunks 2wv, 2wv+1
#pragma unroll
    for (int c = 0; c < 2; ++c) {
        const int jt = wv * 2 + c;
        *reinterpret_cast<float4*>(&Bs[0][jt][l * 8]) =
            *reinterpret_cast<const float4*>(WpH + ((size_t)jt * 64 + l) * 8);
    }
    // x prefetch s=0 (one half8 each covers the full k-octet)
    half8 sv = *reinterpret_cast<const half8*>(Srow + h * 8);
    half8 dv = *reinterpret_cast<const half8*>(Drow + h * 8);
    __syncthreads();

    for (int s = 0; s < 32; ++s) {
        const int buf = s & 1;
        float4 bst[2];
        if (s < 31) {                        // B-hi stage loads for s+1
#pragma unroll
            for (int c = 0; c < 2; ++c) {
                const int jt = wv * 2 + c;
                bst[c] = *reinterpret_cast<const float4*>(
                    WpH + ((size_t)((s + 1) * 8 + jt) * 64 + l) * 8);
            }
        }
        half8 xh;
#pragma unroll
        for (int i = 0; i < 8; ++i) {
            const _Float16 t = sv[i] + dv[i];
            xh[i] = t > (_Float16)0.f ? t : (_Float16)0.f;
        }
        if (s < 31) {                        // prefetch next x k-octet
            const int ko = (s + 1) * 16 + h * 8;
            sv = *reinterpret_cast<const half8*>(Srow + ko);
            dv = *reinterpret_cast<const half8*>(Drow + ko);
        }
#pragma unroll
        for (int jt = 0; jt < 8; ++jt) {
            const half8 bh = *reinterpret_cast<const half8*>(&Bs[buf][jt][l * 8]);
            acc[jt] = __builtin_amdgcn_mfma_f32_32x32x16_f16(xh, bh, acc[jt], 0, 0, 0);
        }
        if (s < 31) {
#pragma unroll
            for (int c = 0; c < 2; ++c) {
                const int jt = wv * 2 + c;
                *reinterpret_cast<float4*>(&Bs[buf ^ 1][jt][l * 8]) = bst[c];
            }
        }
        __syncthreads();
    }

    // ---- layer-2 fold + 32-lane reduce + scatter store ----
    float part[16];
#pragma unroll
    for (int r = 0; r < 16; ++r) part[r] = 0.f;
#pragma unroll
    for (int jt = 0; jt < 8; ++jt) {
        const float w2v = w2[jt * 32 + m];
#pragma unroll
        for (int r = 0; r < 16; ++r)
            part[r] = fmaf(fmaxf(acc[jt][r], 0.f), w2v, part[r]);
    }
#pragma unroll
    for (int off = 1; off < 32; off <<= 1)
#pragma unroll
        for (int r = 0; r < 16; ++r) part[r] += __shfl_xor(part[r], off);
    if (m == 0) {
        const float b2v = b2[0];
#pragma unroll
        for (int r = 0; r < 16; ++r) {
            const int row = (r & 3) + 8 * (r >> 2) + 4 * h;
            out[eidx[e0 + wv * 32 + row]] = part[r] + b2v;
        }
    }
}

// ------------------------------ launch ------------------------------------
extern "C" void kernel_launch(void* const* d_in, const int* in_sizes, int n_in,
                              void* d_out, int out_size, void* d_ws, size_t ws_size,
                              hipStream_t stream) {
    (void)in_sizes; (void)n_in; (void)out_size; (void)ws_size;
    const float* x    = (const float*)d_in[0];
    const int*   src  = (const int*)d_in[1];
    const int*   dst  = (const int*)d_in[2];
    const float* nw0  = (const float*)d_in[3];
    const float* nb0  = (const float*)d_in[4];
    const float* nw1  = (const float*)d_in[5];
    const float* nb1  = (const float*)d_in[6];
    const float* g1ws = (const float*)d_in[7];
    const float* g1bs = (const float*)d_in[8];
    const float* g1wd = (const float*)d_in[9];
    const float* g1bd = (const float*)d_in[10];
    const float* g1a  = (const float*)d_in[11];
    const float* g2ws = (const float*)d_in[12];
    const float* g2bs = (const float*)d_in[13];
    const float* g2wd = (const float*)d_in[14];
    const float* g2bd = (const float*)d_in[15];
    const float* g2a  = (const float*)d_in[16];
    const float* ew0  = (const float*)d_in[17];
    const float* eb0  = (const float*)d_in[18];
    const float* ew1  = (const float*)d_in[19];
    const float* eb1  = (const float*)d_in[20];
    const float* ew2  = (const float*)d_in[21];
    const float* eb2  = (const float*)d_in[22];
    float* out = (float*)d_out;

    float* wsF = (float*)d_ws;
    float* h1  = wsF;                       // 20000*128
    float* g2o = wsF + 2560000;             // 20000*256
    float* fsb = wsF + 7680000;             // 20000*256 (NodeMLP scratch)
    float* fdb = wsF + 12800000;            // 20000*256
    float* g1o = wsF + 17920000;            // 20000*256
    // fp16 S/D overlay fsb / fdb regions (dead by S/D-fc time): N x 512 halves
    _Float16* Sh = (_Float16*)(wsF + 7680000);
    _Float16* Dh = (_Float16*)(wsF + 12800000);
    _Float16* fsh = (_Float16*)(wsF + 23040000);   // 20000*256 fp16
    int* wsI     = (int*)(wsF + 28160000);
    int* row_off = wsI;                     // [0, 20016)
    int* cursor  = wsI + 20016;             // [20016, 40032)
    int* eidx    = wsI + 40032;             // [40032, 360032)
    int* srcs    = wsI + 360032;            // [360032, 680032)
    // ---- B-fragment pack region (tail) ----
    _Float16* pkH = (_Float16*)((char*)d_ws + 115361280);
    _Float16* pkL = pkH + (size_t)PACK_TOT * 8;

    // ---- CSR build ----
    hipMemsetAsync(cursor, 0, N_NODES * sizeof(int), stream);
    hist_kernel<<<1250, 256, 0, stream>>>(dst, cursor);
    scan_all_kernel<<<1, 1024, 0, stream>>>(cursor, row_off, cursor);
    scatter_kernel<<<1250, 256, 0, stream>>>(src, dst, cursor, eidx, srcs);

    // ---- merged weight prepack ----
    PackIn pin{ew1, g1ws, g1wd, g2ws, g2wd, ew0, nw0, nw1, pkH, pkL};
    prepack_all_kernel<<<(PACK_TOT + 255) / 256, 256, 0, stream>>>(pin);

    // ---- NodeMLP ----
    {   LinOut lo{{fsb, nullptr, nullptr, nullptr}, {nb0, nullptr, nullptr, nullptr},
                  {nullptr, nullptr, nullptr, nullptr}};
        mfma_linear2_kernel<64, 1, 1, 64, 64, 64, 128, true, 4, 0>
            <<<dim3(625, 1), 256, 0, stream>>>(x, x, pkH + OFF_N0 * 8, pkL + OFF_N0 * 8,
                                               lo, N_NODES); }
    {   LinOut lo{{h1, nullptr, nullptr, nullptr}, {nb1, nullptr, nullptr, nullptr},
                  {nullptr, nullptr, nullptr, nullptr}};
        mfma_linear2_kernel<128, 1, 1, 128, 128, 128, 128, true, 4, 0>
            <<<dim3(625, 1), 256, 0, stream>>>(fsb, fsb, pkH + OFF_N1 * 8, pkL + OFF_N1 * 8,
                                               lo, N_NODES); }

    // ---- GATv2 layer 1: fused fc (src fp16 | dst fp32), fused attention ----
    {   LinOut lo{{nullptr, fdb, nullptr, nullptr}, {g1bs, g1bd, nullptr, nullptr},
                  {fsh, nullptr, nullptr, nullptr}};
        mfma_linear2_kernel<64, 2, 1, 64, 64, 64, 256, false, 4, 2048>
            <<<dim3(625, 2), 256, 0, stream>>>(x, x, pkH + OFF_G1S * 8, pkL + OFF_G1S * 8,
                                               lo, N_NODES); }
    gat_fused_kernel<<<5000, 256, 0, stream>>>(fsh, fdb, g1a, row_off, srcs, g1o);

    // ---- GATv2 layer 2 (128-row blocks: WR=4, TJ=8) ----
    {   LinOut lo{{nullptr, fdb, nullptr, nullptr}, {g2bs, g2bd, nullptr, nullptr},
                  {fsh, nullptr, nullptr, nullptr}};
        mfma_linear2_kernel<256, 8, 4, 256, 256, 256, 256, false, 2, 8192>
            <<<dim3(157, 2), 256, 0, stream>>>(g1o, g1o, pkH + OFF_G2S * 8, pkL + OFF_G2S * 8,
                                               lo, N_NODES); }
    gat_fused_kernel<<<5000, 256, 0, stream>>>(fsh, fdb, g2a, row_off, srcs, g2o);

    // ---- fused S|D precompute, fp16 output (128-row blocks: WR=4, TJ=8) ----
    {   LinOut lo{{nullptr, nullptr, nullptr, nullptr}, {nullptr, nullptr, eb0, eb0 + 256},
                  {Sh, Sh + 256, Dh, Dh + 256}};
        mfma_linear2_kernel<384, 8, 4, 128, 128, 256, 512, false, 2, 12288>
            <<<dim3(157, 4), 256, 0, stream>>>(h1, g2o, pkH + OFF_SW0 * 8, pkL + OFF_SW0 * 8,
                                               lo, N_NODES); }

    // ---- fused EdgeMLP v7 (fp16 S/D, single-product) ----
    edge_mlp7_kernel<<<N_EDGES / 128, 256, 0, stream>>>(Sh, Dh, srcs, eidx, dst,
                                                        pkH + OFF_W1 * 8,
                                                        eb1, ew2, eb2, out);
}